// Round 10
// baseline (566.773 us; speedup 1.0000x reference)
//
#include <hip/hip_runtime.h>
#include <math.h>

#define Dd 128
#define Hh 4
#define DKk 32
#define Mm 5
#define NNn 15
#define Bb 1024
#define Nn 64
#define MN 75
#define BN 65536
#define RSQRT_DK 0.17677669529663687f

typedef __attribute__((ext_vector_type(8))) short bf16x8;
typedef __attribute__((ext_vector_type(4))) float f32x4;

__device__ __forceinline__ ushort f2bf(float x) {
    unsigned u = __float_as_uint(x);
    u = (u + 0x7fffu + ((u >> 16) & 1u)) >> 16;
    return (ushort)u;
}
__device__ __forceinline__ float bf2f(ushort h) {
    return __uint_as_float(((unsigned)h) << 16);
}
__device__ __forceinline__ void split2(float x, ushort& hi, ushort& lo) {
    hi = f2bf(x);
    lo = f2bf(x - bf2f(hi));
}
__device__ __forceinline__ f32x4 MFMA(bf16x8 a, bf16x8 b, f32x4 c) {
    return __builtin_amdgcn_mfma_f32_16x16x32_bf16(a, b, c, 0, 0, 0);
}
__device__ __forceinline__ bf16x8 mk8(unsigned u0, unsigned u1, unsigned u2, unsigned u3) {
    union { unsigned u[4]; bf16x8 v; } x;
    x.u[0] = u0; x.u[1] = u1; x.u[2] = u2; x.u[3] = u3;
    return x.v;
}

// nimT XOR swizzle: row pitch 128 elements; flip col bits 3..5 by row&7.
#define NSWZ(r, c) ((r) * 128 + ((c) ^ (((r) & 7) << 3)))

// ---------------------------------------------------------------------------
// k0: weight preprocessing. Round-6 + maskT80 (m*16-packed transposed mask).
// ---------------------------------------------------------------------------
__global__ void k0_prep(const float* __restrict__ maskm,
                        const float* __restrict__ WK, const float* __restrict__ bK,
                        const float* __restrict__ WQ, const float* __restrict__ bQ,
                        const float* __restrict__ WM, const float* __restrict__ bM,
                        const float* __restrict__ WB, const float* __restrict__ bB,
                        const float* __restrict__ Wu, const float* __restrict__ Wd,
                        const float* __restrict__ Wl, const float* __restrict__ Wr,
                        ushort* __restrict__ WKhi, ushort* __restrict__ WKlo,
                        ushort* __restrict__ WQhi, ushort* __restrict__ WQlo,
                        ushort* __restrict__ WMhi, ushort* __restrict__ WBhi,
                        ushort* __restrict__ maskhi, ushort* __restrict__ masklo,
                        ushort* __restrict__ maskThi, ushort* __restrict__ maskTlo,
                        ushort* __restrict__ maskT80hi, ushort* __restrict__ maskT80lo,
                        float* __restrict__ btKT, float* __restrict__ btQT,
                        float* __restrict__ btMT, float* __restrict__ btB,
                        ushort* __restrict__ WcatT)
{
    int tid = blockIdx.x * blockDim.x + threadIdx.x;
    int nthr = gridDim.x * blockDim.x;
    const int NW = Mm * Dd * Dd;  // 81920
    for (int i = tid; i < NW; i += nthr) {
        split2(WK[i], WKhi[i], WKlo[i]);
        split2(WQ[i], WQhi[i], WQlo[i]);
        WMhi[i] = f2bf(WM[i]);
        WBhi[i] = f2bf(WB[i]);
    }
    for (int i = tid; i < 96 * 64; i += nthr) {
        float v = (i < MN * 64) ? maskm[i] : 0.f;
        split2(v, maskhi[i], masklo[i]);
    }
    // old transposed mask [col][j=m*15+jj packed, 96 wide]
    for (int i = tid; i < 64 * 96; i += nthr) {
        int col = i / 96, j = i - col * 96;
        float v = (j < MN) ? maskm[j * 64 + col] : 0.f;
        split2(v, maskThi[i], maskTlo[i]);
    }
    // new transposed mask [col][jt=m*16+jj packed, 96 wide]; zero at jj=15, jt>=80
    for (int i = tid; i < 64 * 96; i += nthr) {
        int col = i / 96, jt = i - col * 96;
        int m = jt >> 4, jj = jt & 15;
        float v = (jt < 80 && jj < 15) ? maskm[(m * 15 + jj) * 64 + col] : 0.f;
        split2(v, maskT80hi[i], maskT80lo[i]);
    }
    for (int i = tid; i < 4096; i += nthr) {
        int q = i >> 5, kk = i & 31;
        const float* Wsel = (q < 32) ? Wu : (q < 64) ? Wd : (q < 96) ? Wl : Wr;
        WcatT[i] = f2bf(Wsel[kk * 32 + (q & 31)]);
    }
    for (int i = tid; i < 8192; i += nthr) {
        int d = i >> 6, col = i & 63;
        float aKv = 0.f, aQv = 0.f, aBv = 0.f;
        for (int m = 0; m < Mm; ++m) {
            float mrs = 0.f;
            for (int N = 0; N < NNn; ++N) mrs += maskm[(m * 15 + N) * 64 + col];
            aKv += bK[m * 128 + d] * mrs;
            aQv += bQ[m * 128 + d] * mrs;
            aBv += bB[m * 128 + d] * mrs;
        }
        btKT[col * 128 + d] = aKv;
        btQT[col * 128 + d] = aQv;
        btB[i] = aBv;
        float aMv = 0.f;
        for (int j = 0; j < MN; ++j) {
            int f = d * 75 + j;
            int m = f / 1920;
            int dloc = (f / 15) & 127;
            aMv += bM[m * 128 + dloc] * maskm[j * 64 + col];
        }
        btMT[col * 128 + d] = aMv;
    }
}

// ---------------------------------------------------------------------------
// k1 v10: 256 threads, 40.7KB LDS -> 4 blocks/CU (grid 1024 = one clean
// round). 3 barriers total. Y never touches LDS: Y^T computed per wave
// (A=nimT, B=W row-major global) and regathered into mask-GEMM B-frags via
// __shfl + select. Garbage j-rows clamped (l15==15 -> 14), killed by
// maskT80's zero columns. msg path: xM overlays nimTl (r9-proven).
// ---------------------------------------------------------------------------
__global__ __launch_bounds__(256, 4) void k1_proj(
    const float* __restrict__ node, const float* __restrict__ WW,
    const ushort* __restrict__ WKhi, const ushort* __restrict__ WKlo,
    const ushort* __restrict__ WQhi, const ushort* __restrict__ WQlo,
    const ushort* __restrict__ WMhi,
    const ushort* __restrict__ maskThi,
    const ushort* __restrict__ maskT80hi, const ushort* __restrict__ maskT80lo,
    const float* __restrict__ btKT, const float* __restrict__ btQT,
    const float* __restrict__ btMT,
    ushort* __restrict__ Khi, ushort* __restrict__ Klo,
    ushort* __restrict__ Qhi, ushort* __restrict__ Qlo,
    ushort* __restrict__ msgTg)
{
    const int b = blockIdx.x;
    const int tid = threadIdx.x;
    const int lane = tid & 63, w = tid >> 6;      // w in 0..3
    const int l15 = lane & 15, lq = lane >> 4;
    const int lcl = (l15 < 15) ? l15 : 14;        // clamped row (finite garbage)

    __shared__ __align__(16) ushort nimTh[79 * 128];        // 20224 B
    __shared__ __align__(16) ushort nimTl[80 * 128 + 16];   // 20512 B (xM overlay)
    ushort* xM = nimTl;                                     // [128][80] flat

    const f32x4 zz = {0.f, 0.f, 0.f, 0.f};

    // ---- p0: nimT = (node @ WW_m)^T, split x split (3 chains), 2 e-blocks ----
    for (int s = 0; s < 2; ++s) {
        int eb = w * 2 + s;
        bf16x8 ah[2], al[2];
        #pragma unroll
        for (int ks = 0; ks < 2; ++ks) {
            const float* np = node + (size_t)(eb * 16 + l15) * BN + b * 64 + ks * 32 + lq * 8;
            float tmp[8];
            *(float4*)tmp       = *(const float4*)np;
            *(float4*)(tmp + 4) = *(const float4*)(np + 4);
            #pragma unroll
            for (int j = 0; j < 8; ++j) {
                ushort h_, l_; split2(tmp[j], h_, l_);
                ah[ks][j] = (short)h_; al[ks][j] = (short)l_;
            }
        }
        for (int m = 0; m < Mm; ++m) {
            const float* wp = WW + ((size_t)b * Mm + m) * 960 + (l15 < 15 ? l15 : 0);
            f32x4 chh = zz, chl = zz, clh = zz;
            #pragma unroll
            for (int ks = 0; ks < 2; ++ks) {
                bf16x8 bh, bl;
                #pragma unroll
                for (int t = 0; t < 8; ++t) {
                    int n = ks * 32 + lq * 8 + t;
                    float v = (l15 < 15) ? wp[n * 15] : 0.f;
                    ushort h_, l_; split2(v, h_, l_);
                    bh[t] = (short)h_; bl[t] = (short)l_;
                }
                chh = MFMA(ah[ks], bh, chh);
                chl = MFMA(ah[ks], bl, chl);
                clh = MFMA(al[ks], bh, clh);
            }
            f32x4 c = chh + chl + clh;
            if (l15 < 15) {
                int row = m * 16 + l15;
                #pragma unroll
                for (int t = 0; t < 4; ++t) {
                    int e = eb * 16 + lq * 4 + t;
                    split2(c[t], nimTh[NSWZ(row, e)], nimTl[NSWZ(row, e)]);
                }
            }
        }
    }
    __syncthreads();   // barrier 1

    // ---- K/Q: per wave, combos (P=0,dct=w) and (P=1,dct=w); no barriers ----
    const int sAl = ((lq & 1) << 5) + l15;   // shfl source lane A
    const int sBl = sAl + 16;                // shfl source lane B
    const bool hiT = (lq >= 2);

    for (int P = 0; P < 2; ++P) {
        const ushort* Whi = P ? WQhi : WKhi;
        const ushort* Wlo = P ? WQlo : WKlo;
        const float*  btP = P ? btQT : btKT;
        ushort* Phi = P ? Qhi : Khi;
        ushort* Plo = P ? Qlo : Klo;
        const int dct = w;

        for (int dt = 0; dt < 2; ++dt) {
            // Y^T tiles: C'_m[jl][dcol], packed bf16 hi/lo pairs per lane
            unsigned pkh0[5], pkh1[5], pkl0[5], pkl1[5];
            #pragma unroll
            for (int m = 0; m < Mm; ++m) {
                int arow = m * 16 + lcl;
                int wrow = dct * 32 + dt * 16 + l15;
                f32x4 chh = zz, chl = zz, clh = zz;
                #pragma unroll
                for (int ks = 0; ks < 4; ++ks) {
                    int k0 = ks * 32 + lq * 8;
                    bf16x8 anh = *(const bf16x8*)&nimTh[NSWZ(arow, k0)];
                    bf16x8 anl = *(const bf16x8*)&nimTl[NSWZ(arow, k0)];
                    size_t wo = (size_t)m * 16384 + (size_t)wrow * 128 + k0;
                    bf16x8 bwh = *(const bf16x8*)(Whi + wo);
                    bf16x8 bwl = *(const bf16x8*)(Wlo + wo);
                    chh = MFMA(anh, bwh, chh);
                    chl = MFMA(anh, bwl, chl);
                    clh = MFMA(anl, bwh, clh);
                }
                f32x4 c = chh + chl + clh;
                ushort h0, h1, h2, h3, l0, l1, l2, l3;
                split2(c[0], h0, l0); split2(c[1], h1, l1);
                split2(c[2], h2, l2); split2(c[3], h3, l3);
                pkh0[m] = (unsigned)h0 | ((unsigned)h1 << 16);
                pkh1[m] = (unsigned)h2 | ((unsigned)h3 << 16);
                pkl0[m] = (unsigned)l0 | ((unsigned)l1 << 16);
                pkl1[m] = (unsigned)l2 | ((unsigned)l3 << 16);
            }
            // mask-GEMM: C2[n][dcol] = sum_j maskT80[n][j] * Y^T[j][dcol]
            f32x4 aH[4] = {zz, zz, zz, zz};
            f32x4 aX[4] = {zz, zz, zz, zz};
            #pragma unroll
            for (int ks = 0; ks < 3; ++ks) {
                const int mA = ks * 2;
                const int mB = (ks * 2 + 1 < 5) ? ks * 2 + 1 : 4;  // phantom tile 5 -> dup (x0)
                unsigned a0, b0c;
                bf16x8 yH, yL;
                {
                    unsigned u0, u1, u2, u3;
                    a0 = __shfl((int)pkh0[mA], sAl); b0c = __shfl((int)pkh0[mB], sAl);
                    u0 = hiT ? b0c : a0;
                    a0 = __shfl((int)pkh1[mA], sAl); b0c = __shfl((int)pkh1[mB], sAl);
                    u1 = hiT ? b0c : a0;
                    a0 = __shfl((int)pkh0[mA], sBl); b0c = __shfl((int)pkh0[mB], sBl);
                    u2 = hiT ? b0c : a0;
                    a0 = __shfl((int)pkh1[mA], sBl); b0c = __shfl((int)pkh1[mB], sBl);
                    u3 = hiT ? b0c : a0;
                    yH = mk8(u0, u1, u2, u3);
                    a0 = __shfl((int)pkl0[mA], sAl); b0c = __shfl((int)pkl0[mB], sAl);
                    u0 = hiT ? b0c : a0;
                    a0 = __shfl((int)pkl1[mA], sAl); b0c = __shfl((int)pkl1[mB], sAl);
                    u1 = hiT ? b0c : a0;
                    a0 = __shfl((int)pkl0[mA], sBl); b0c = __shfl((int)pkl0[mB], sBl);
                    u2 = hiT ? b0c : a0;
                    a0 = __shfl((int)pkl1[mA], sBl); b0c = __shfl((int)pkl1[mB], sBl);
                    u3 = hiT ? b0c : a0;
                    yL = mk8(u0, u1, u2, u3);
                }
                #pragma unroll
                for (int nt = 0; nt < 4; ++nt) {
                    int mr = (nt * 16 + l15) * 96 + ks * 32 + lq * 8;
                    bf16x8 mh = *(const bf16x8*)(maskT80hi + mr);
                    bf16x8 ml = *(const bf16x8*)(maskT80lo + mr);
                    aH[nt] = MFMA(mh, yH, aH[nt]);
                    aX[nt] = MFMA(ml, yH, aX[nt]);
                    aX[nt] = MFMA(mh, yL, aX[nt]);
                }
            }
            // store
            #pragma unroll
            for (int nt = 0; nt < 4; ++nt) {
                f32x4 c = aH[nt] + aX[nt];
                #pragma unroll
                for (int r = 0; r < 4; ++r) {
                    int n = nt * 16 + lq * 4 + r;
                    int dpr = dct * 32 + dt * 16 + l15;
                    size_t oi = (((size_t)(b * 4 + dct)) * 64 + n) * 32 + dt * 16 + l15;
                    ushort hh_, ll_;
                    split2(c[r] + btP[n * 128 + dpr], hh_, ll_);
                    Phi[oi] = hh_; Plo[oi] = ll_;
                }
            }
        }
    }
    __syncthreads();   // barrier 2 (all reads of nimTl done before xM overlay)

    // ---- msg scatter: xM[128][80] overlays nimTl; reads nimTh only ----
    for (int t = tid; t < 128 * 5; t += 256) {
        int r = t / 5, cc = 75 + (t - r * 5);
        xM[r * 80 + cc] = 0;
    }
    for (int t = tid; t < 16; t += 256) xM[10240 + t] = 0;   // OOB-read pad
    for (int s = 0; s < 2; ++s) {
        int rt = w * 2 + s;
        for (int m = 0; m < Mm; ++m) {
            f32x4 c0 = zz, c1 = zz;
            int arow = m * 16 + lcl;
            #pragma unroll
            for (int ks = 0; ks < 4; ++ks) {
                int k0 = ks * 32 + lq * 8;
                bf16x8 a  = *(const bf16x8*)(WMhi + (size_t)m * 16384 + (size_t)(rt * 16 + l15) * 128 + k0);
                bf16x8 bh = *(const bf16x8*)&nimTh[NSWZ(arow, k0)];
                if (ks < 2) c0 = MFMA(a, bh, c0); else c1 = MFMA(a, bh, c1);
            }
            f32x4 c = c0 + c1;
            if (l15 < 15) {
                #pragma unroll
                for (int t = 0; t < 4; ++t) {
                    int dflat = rt * 16 + lq * 4 + t;
                    int g = m * 1920 + dflat * 15 + l15;
                    xM[(g / 75) * 80 + (g % 75)] = f2bf(c[t]);
                }
            }
        }
    }
    __syncthreads();   // barrier 3

    // ---- msg mask (swapped, single bf16): 32 units, 8 per wave ----
    #pragma unroll
    for (int s2 = 0; s2 < 8; ++s2) {
        int u = w * 8 + s2;
        int nr = u & 3, ddc = u >> 2;
        f32x4 cs0 = zz, cs1 = zz, cs2 = zz;
        {
            bf16x8 a0 = *(const bf16x8*)(maskThi + (nr * 16 + l15) * 96 + lq * 8);
            bf16x8 b0 = *(const bf16x8*)(&xM[(ddc * 16 + l15) * 80 + lq * 8]);
            cs0 = MFMA(a0, b0, cs0);
            bf16x8 a1 = *(const bf16x8*)(maskThi + (nr * 16 + l15) * 96 + 32 + lq * 8);
            bf16x8 b1 = *(const bf16x8*)(&xM[(ddc * 16 + l15) * 80 + 32 + lq * 8]);
            cs1 = MFMA(a1, b1, cs1);
            bf16x8 a2 = *(const bf16x8*)(maskThi + (nr * 16 + l15) * 96 + 64 + lq * 8);
            bf16x8 b2 = *(const bf16x8*)(&xM[(ddc * 16 + l15) * 80 + 64 + lq * 8]);
            cs2 = MFMA(a2, b2, cs2);
        }
        f32x4 c = cs0 + cs1 + cs2;
        #pragma unroll
        for (int t = 0; t < 4; ++t) {
            int n = nr * 16 + lq * 4 + t;
            int dd = ddc * 16 + l15;
            int h = dd >> 5, dk = dd & 31;
            msgTg[(((size_t)(b * 4 + h)) * 64 + n) * 32 + dk] = f2bf(c[t] + btMT[n * 128 + dd]);
        }
    }
}

// ---------------------------------------------------------------------------
// k2 v6 (round-6 verbatim): global-direct fragments, 44.3KB LDS.
// ---------------------------------------------------------------------------
__global__ __launch_bounds__(512, 4) void k2_attn(
    const ushort* __restrict__ Khi, const ushort* __restrict__ Klo,
    const ushort* Qhi, const ushort* __restrict__ Qlo,
    const ushort* __restrict__ msgTg,
    const float* __restrict__ R, const float* __restrict__ am,
    const ushort* __restrict__ WcatT, float* __restrict__ aw00,
    ushort* Bout)
{
    const int b = blockIdx.x >> 2, h = blockIdx.x & 3;
    const int tid = threadIdx.x;
    const int lane = tid & 63, w = tid >> 6;
    const int l15 = lane & 15, lq = lane >> 4;

    __shared__ float  ST[64 * 65];
    __shared__ ushort resS[128 * 72];
    __shared__ ushort awq[64 * 72];

    const f32x4 zz = {0.f, 0.f, 0.f, 0.f};
    const size_t base2 = (size_t)(b * 4 + h) * 2048;
    const float* Rb = R + (size_t)(b * 4 + h) * 4096;

    {
        int ti = w >> 1;
        bf16x8 ah = *(const bf16x8*)(Qhi + base2 + (size_t)(ti * 16 + l15) * 32 + lq * 8);
        bf16x8 al = *(const bf16x8*)(Qlo + base2 + (size_t)(ti * 16 + l15) * 32 + lq * 8);
        #pragma unroll
        for (int s = 0; s < 2; ++s) {
            int tj = (w & 1) * 2 + s;
            bf16x8 bh = *(const bf16x8*)(Khi + base2 + (size_t)(tj * 16 + l15) * 32 + lq * 8);
            bf16x8 bl = *(const bf16x8*)(Klo + base2 + (size_t)(tj * 16 + l15) * 32 + lq * 8);
            f32x4 chh = zz, chl = zz, clh = zz;
            chh = MFMA(ah, bh, chh); chl = MFMA(ah, bl, chl); clh = MFMA(al, bh, clh);
            f32x4 c = chh + chl + clh;
            #pragma unroll
            for (int r = 0; r < 4; ++r) {
                int i = ti * 16 + lq * 4 + r, j = tj * 16 + l15;
                ST[j * 65 + i] = Rb[i * 64 + j] + c[r] * RSQRT_DK;
            }
        }
    }
    {
        bf16x8 a = *(const bf16x8*)(WcatT + (w * 16 + l15) * 32 + lq * 8);
        #pragma unroll
        for (int nt = 0; nt < 4; ++nt) {
            bf16x8 bfr = *(const bf16x8*)(msgTg + base2 + (size_t)(nt * 16 + l15) * 32 + lq * 8);
            f32x4 c = MFMA(a, bfr, zz);
            #pragma unroll
            for (int r = 0; r < 4; ++r)
                resS[(w * 16 + lq * 4 + r) * 72 + nt * 16 + l15] = f2bf(c[r]);
        }
    }
    __syncthreads();

    {
        int row = tid >> 3, part = tid & 7;
        float v[8]; float mx = -INFINITY;
        #pragma unroll
        for (int jj = 0; jj < 8; ++jj) { v[jj] = ST[(part * 8 + jj) * 65 + row]; mx = fmaxf(mx, v[jj]); }
        mx = fmaxf(mx, __shfl_xor(mx, 1));
        mx = fmaxf(mx, __shfl_xor(mx, 2));
        mx = fmaxf(mx, __shfl_xor(mx, 4));
        float s = 0.f;
        #pragma unroll
        for (int jj = 0; jj < 8; ++jj) { v[jj] = expf(v[jj] - mx); s += v[jj]; }
        s += __shfl_xor(s, 1); s += __shfl_xor(s, 2); s += __shfl_xor(s, 4);
        float inv = 1.f / s;
        #pragma unroll
        for (int jj = 0; jj < 8; ++jj) {
            float p = v[jj] * inv;
            ST[(part * 8 + jj) * 65 + row] = isnan(p) ? 0.f : p;
        }
    }
    __syncthreads();

    const int kt = w >> 2, it = w & 3;
    f32x4 accB0 = zz, accB1 = zz;
    for (int q = 0; q < 4; ++q) {
        for (int e = tid; e < 4096; e += 512) {
            int i = e >> 6, j0 = e & 63;
            float p = ST[j0 * 65 + i] * am[i * 256 + q * 64 + j0];
            awq[i * 72 + j0] = f2bf(p);
            if (blockIdx.x == 0) aw00[i * 256 + q * 64 + j0] = p;
        }
        __syncthreads();
        int row = 4 * (kt * 16 + l15) + q;
        bf16x8 a0 = *(const bf16x8*)(&resS[row * 72 + lq * 8]);
        bf16x8 b0 = *(const bf16x8*)(&awq[(it * 16 + l15) * 72 + lq * 8]);
        accB0 = MFMA(a0, b0, accB0);
        bf16x8 a1 = *(const bf16x8*)(&resS[row * 72 + 32 + lq * 8]);
        bf16x8 b1 = *(const bf16x8*)(&awq[(it * 16 + l15) * 72 + 32 + lq * 8]);
        accB1 = MFMA(a1, b1, accB1);
        __syncthreads();
    }
    f32x4 accB = accB0 + accB1;

    #pragma unroll
    for (int r = 0; r < 4; ++r) {
        int k = kt * 16 + lq * 4 + r, i = it * 16 + l15;
        float x = accB[r];
        float g = 0.5f * x * (1.f + erff(x * 0.70710678118654752f));
        Bout[base2 + k * 64 + i] = f2bf(g);
    }
}

// ---------------------------------------------------------------------------
// k3 (round-6 verbatim): per-b output projection + residual.
// ---------------------------------------------------------------------------
__global__ __launch_bounds__(512, 4) void k3_out(
    const ushort* Bbuf, const float* __restrict__ WW,
    const ushort* __restrict__ WBhi, const ushort* __restrict__ maskhi,
    const float* __restrict__ btB, const float* __restrict__ node,
    float* __restrict__ outp)
{
    const int b = blockIdx.x, tid = threadIdx.x;
    const int lane = tid & 63, w = tid >> 6, l15 = lane & 15, lq = lane >> 4;
    __shared__ ushort sB[128 * 72];
    __shared__ ushort wwh[64 * 17];
    __shared__ ushort t1[128 * 17];
    __shared__ ushort nm[32 * 66];

    for (int i = tid; i < 8192; i += 512) {
        int d = i >> 6, n = i & 63;
        sB[d * 72 + n] = Bbuf[(size_t)b * 8192 + i];
    }
    const f32x4 zz = {0.f, 0.f, 0.f, 0.f};
    f32x4 acc[4];
    for (int c = 0; c < 4; ++c) acc[c] = zz;
    __syncthreads();

    for (int m = 0; m < Mm; ++m) {
        for (int i = tid; i < 64 * 17; i += 512) {
            int n = i / 17, N = i - n * 17;
            wwh[i] = (N < 15) ? f2bf(WW[(((size_t)b * Mm + m) * 64 + n) * 15 + N]) : (ushort)0;
        }
        __syncthreads();
        {
            f32x4 c0 = zz, c1 = zz;
            #pragma unroll
            for (int ks = 0; ks < 2; ++ks) {
                int k0 = ks * 32 + (lq << 3);
                bf16x8 a = *(const bf16x8*)(&sB[(w * 16 + l15) * 72 + k0]);
                bf16x8 bh;
                #pragma unroll
                for (int t = 0; t < 8; ++t) bh[t] = (short)wwh[(k0 + t) * 17 + l15];
                if (ks == 0) c0 = MFMA(a, bh, c0); else c1 = MFMA(a, bh, c1);
            }
            f32x4 c = c0 + c1;
            #pragma unroll
            for (int t = 0; t < 4; ++t)
                t1[(w * 16 + lq * 4 + t) * 17 + l15] = f2bf(c[t]);
        }
        __syncthreads();

        bf16x8 mfh;
        {
            int ct = w & 3;
            int k0 = lq << 3;
            #pragma unroll
            for (int t = 0; t < 8; ++t) {
                int kk = k0 + t;
                int row = (kk < 15) ? (m * 15 + kk) : 95;
                mfh[t] = (short)maskhi[row * 64 + ct * 16 + l15];
            }
        }
        for (int eb = 0; eb < 4; ++eb) {
            {
                int rtl = w >> 2, ct = w & 3;
                int e = eb * 32 + rtl * 16 + l15;
                int k0 = lq << 3;
                bf16x8 a;
                #pragma unroll
                for (int t = 0; t < 8; ++t) {
                    int kk = k0 + t;
                    int cc = (kk < 15) ? kk : 15;
                    a[t] = (short)t1[e * 17 + cc];
                }
                f32x4 c = zz;
                c = MFMA(a, mfh, c);
                #pragma unroll
                for (int t = 0; t < 4; ++t)
                    nm[(rtl * 16 + lq * 4 + t) * 66 + ct * 16 + l15] = f2bf(c[t]);
            }
            __syncthreads();
            {
                size_t aoff = (size_t)(w * 16 + l15) * 128 + eb * 32 + (lq << 3);
                bf16x8 a = *(const bf16x8*)(WBhi + m * 16384 + aoff);
                int k0 = lq << 3;
                #pragma unroll
                for (int ct = 0; ct < 4; ++ct) {
                    bf16x8 bh;
                    #pragma unroll
                    for (int t = 0; t < 8; ++t) bh[t] = (short)nm[(k0 + t) * 66 + ct * 16 + l15];
                    acc[ct] = MFMA(a, bh, acc[ct]);
                }
            }
            __syncthreads();
        }
    }
    #pragma unroll
    for (int ct = 0; ct < 4; ++ct) {
        #pragma unroll
        for (int t = 0; t < 4; ++t) {
            int d = w * 16 + lq * 4 + t;
            int col = ct * 16 + l15;
            size_t gi = (size_t)d * BN + b * 64 + col;
            outp[gi] = acc[ct][t] + btB[d * 64 + col] + node[gi];
        }
    }
}

extern "C" void kernel_launch(void* const* d_in, const int* in_sizes, int n_in,
                              void* d_out, int out_size, void* d_ws, size_t ws_size,
                              hipStream_t stream) {
    const float* node  = (const float*)d_in[0];
    const float* WW    = (const float*)d_in[1];
    const float* maskm = (const float*)d_in[2];
    const float* R     = (const float*)d_in[3];
    const float* am    = (const float*)d_in[4];
    const float* WK = (const float*)d_in[5];  const float* bK = (const float*)d_in[6];
    const float* WQ = (const float*)d_in[7];  const float* bQ = (const float*)d_in[8];
    const float* WM = (const float*)d_in[9];  const float* bM = (const float*)d_in[10];
    const float* WB = (const float*)d_in[11]; const float* bB = (const float*)d_in[12];
    const float* Wu = (const float*)d_in[13]; const float* Wd = (const float*)d_in[14];
    const float* Wl = (const float*)d_in[15]; const float* Wr = (const float*)d_in[16];

    float* out  = (float*)d_out;
    float* aw00 = out + (size_t)Dd * BN;

    // K split planes fill the out region (dead before k3 writes out)
    ushort* Khi = (ushort*)d_out;
    ushort* Klo = Khi + 8388608;

    char* W = (char*)d_ws;
    ushort* Qhi   = (ushort*)W;                   // 16.78MB (also Bout/Bbuf)
    ushort* Qlo   = Qhi + 8388608;                // 16.78MB
    ushort* msgTg = Qlo + 8388608;                // 16.78MB
    ushort* WKhi  = msgTg + 8388608;
    ushort* WKlo  = WKhi + 81920;
    ushort* WQhi  = WKlo + 81920;
    ushort* WQlo  = WQhi + 81920;
    ushort* WMhi  = WQlo + 81920;
    ushort* WBhi  = WMhi + 81920;
    ushort* maskhi  = WBhi + 81920;
    ushort* masklo  = maskhi + 6144;
    ushort* maskThi = masklo + 6144;
    ushort* maskTlo = maskThi + 6144;
    ushort* maskT80hi = maskTlo + 6144;
    ushort* maskT80lo = maskT80hi + 6144;
    ushort* WcatT   = maskT80lo + 6144;
    float*  btKT = (float*)(WcatT + 4096);
    float*  btQT = btKT + 8192;
    float*  btMT = btQT + 8192;
    float*  btB  = btMT + 8192;

    k0_prep<<<512, 256, 0, stream>>>(maskm, WK, bK, WQ, bQ, WM, bM, WB, bB,
                                     Wu, Wd, Wl, Wr,
                                     WKhi, WKlo, WQhi, WQlo, WMhi, WBhi,
                                     maskhi, masklo, maskThi, maskTlo,
                                     maskT80hi, maskT80lo,
                                     btKT, btQT, btMT, btB, WcatT);
    k1_proj<<<Bb, 256, 0, stream>>>(node, WW, WKhi, WKlo, WQhi, WQlo, WMhi,
                                    maskThi, maskT80hi, maskT80lo,
                                    btKT, btQT, btMT,
                                    Khi, Klo, Qhi, Qlo, msgTg);
    k2_attn<<<Bb * Hh, 512, 0, stream>>>(Khi, Klo, Qhi, Qlo, msgTg, R, am,
                                         WcatT, aw00, Qhi /*Bout overlay*/);
    k3_out<<<Bb, 512, 0, stream>>>(Qhi /*Bbuf*/, WW, WBhi, maskhi, btB, node, out);
}

// Round 11
// 297.741 us; speedup vs baseline: 1.9036x; 1.9036x over previous
//
#include <hip/hip_runtime.h>
#include <math.h>

#define Dd 128
#define Hh 4
#define DKk 32
#define Mm 5
#define NNn 15
#define Bb 1024
#define Nn 64
#define MN 75
#define BN 65536
#define RSQRT_DK 0.17677669529663687f

typedef __attribute__((ext_vector_type(8))) short bf16x8;
typedef __attribute__((ext_vector_type(4))) float f32x4;

__device__ __forceinline__ ushort f2bf(float x) {
    unsigned u = __float_as_uint(x);
    u = (u + 0x7fffu + ((u >> 16) & 1u)) >> 16;
    return (ushort)u;
}
__device__ __forceinline__ float bf2f(ushort h) {
    return __uint_as_float(((unsigned)h) << 16);
}
__device__ __forceinline__ void split2(float x, ushort& hi, ushort& lo) {
    hi = f2bf(x);
    lo = f2bf(x - bf2f(hi));
}
__device__ __forceinline__ f32x4 MFMA(bf16x8 a, bf16x8 b, f32x4 c) {
    return __builtin_amdgcn_mfma_f32_16x16x32_bf16(a, b, c, 0, 0, 0);
}

// ---------------------------------------------------------------------------
// k0: weight preprocessing (tiny, every call). Round-6 verbatim.
// ---------------------------------------------------------------------------
__global__ void k0_prep(const float* __restrict__ maskm,
                        const float* __restrict__ WK, const float* __restrict__ bK,
                        const float* __restrict__ WQ, const float* __restrict__ bQ,
                        const float* __restrict__ WM, const float* __restrict__ bM,
                        const float* __restrict__ WB, const float* __restrict__ bB,
                        const float* __restrict__ Wu, const float* __restrict__ Wd,
                        const float* __restrict__ Wl, const float* __restrict__ Wr,
                        ushort* __restrict__ WKhi, ushort* __restrict__ WKlo,
                        ushort* __restrict__ WQhi, ushort* __restrict__ WQlo,
                        ushort* __restrict__ WMhi, ushort* __restrict__ WBhi,
                        ushort* __restrict__ maskhi, ushort* __restrict__ masklo,
                        ushort* __restrict__ maskThi, ushort* __restrict__ maskTlo,
                        float* __restrict__ btKT, float* __restrict__ btQT,
                        float* __restrict__ btMT, float* __restrict__ btB,
                        ushort* __restrict__ WcatT)
{
    int tid = blockIdx.x * blockDim.x + threadIdx.x;
    int nthr = gridDim.x * blockDim.x;
    const int NW = Mm * Dd * Dd;  // 81920
    for (int i = tid; i < NW; i += nthr) {
        split2(WK[i], WKhi[i], WKlo[i]);
        split2(WQ[i], WQhi[i], WQlo[i]);
        WMhi[i] = f2bf(WM[i]);
        WBhi[i] = f2bf(WB[i]);
    }
    for (int i = tid; i < 96 * 64; i += nthr) {
        float v = (i < MN * 64) ? maskm[i] : 0.f;
        split2(v, maskhi[i], masklo[i]);
    }
    for (int i = tid; i < 64 * 96; i += nthr) {
        int col = i / 96, j = i - col * 96;
        float v = (j < MN) ? maskm[j * 64 + col] : 0.f;
        split2(v, maskThi[i], maskTlo[i]);
    }
    for (int i = tid; i < 4096; i += nthr) {
        int q = i >> 5, kk = i & 31;
        const float* Wsel = (q < 32) ? Wu : (q < 64) ? Wd : (q < 96) ? Wl : Wr;
        WcatT[i] = f2bf(Wsel[kk * 32 + (q & 31)]);
    }
    for (int i = tid; i < 8192; i += nthr) {
        int d = i >> 6, col = i & 63;
        float aKv = 0.f, aQv = 0.f, aBv = 0.f;
        for (int m = 0; m < Mm; ++m) {
            float mrs = 0.f;
            for (int N = 0; N < NNn; ++N) mrs += maskm[(m * 15 + N) * 64 + col];
            aKv += bK[m * 128 + d] * mrs;
            aQv += bQ[m * 128 + d] * mrs;
            aBv += bB[m * 128 + d] * mrs;
        }
        btKT[col * 128 + d] = aKv;
        btQT[col * 128 + d] = aQv;
        btB[i] = aBv;
        float aMv = 0.f;
        for (int j = 0; j < MN; ++j) {
            int f = d * 75 + j;
            int m = f / 1920;
            int dloc = (f / 15) & 127;
            aMv += bM[m * 128 + dloc] * maskm[j * 64 + col];
        }
        btMT[col * 128 + d] = aMv;
    }
}

// ---------------------------------------------------------------------------
// k1 v11 = round-6 v6 data path EXACTLY, with rolled outer loops
// (#pragma unroll 1) to keep the code image I$-resident. LDS 70,144B.
// ---------------------------------------------------------------------------
__global__ __launch_bounds__(512, 4) void k1_proj(
    const float* __restrict__ node, const float* __restrict__ WW,
    const ushort* __restrict__ WKhi, const ushort* __restrict__ WKlo,
    const ushort* __restrict__ WQhi, const ushort* __restrict__ WQlo,
    const ushort* __restrict__ WMhi,
    const ushort* __restrict__ maskThi, const ushort* __restrict__ maskTlo,
    const float* __restrict__ btKT, const float* __restrict__ btQT,
    const float* __restrict__ btMT,
    ushort* __restrict__ Khi, ushort* __restrict__ Klo,
    ushort* __restrict__ Qhi, ushort* __restrict__ Qlo,
    ushort* __restrict__ msgTg)
{
    const int b = blockIdx.x;
    const int tid = threadIdx.x;
    const int lane = tid & 63, w = tid >> 6;
    const int l15 = lane & 15, lq = lane >> 4;

    __shared__ ushort nimTh[80 * 136];        // [m*16+N][e] pitch 136
    __shared__ ushort nimTl[80 * 136];
    __shared__ ushort planes[4 * 32 * 104];   // Ykh|Ykl|Yqh|Yql ; later xM[128][104]

    ushort* Ykh = planes;
    ushort* Ykl = planes + 32 * 104;
    ushort* Yqh = planes + 2 * 32 * 104;
    ushort* Yql = planes + 3 * 32 * 104;

    for (int t = tid; t < 5 * 136; t += 512) {
        int mm = t / 136, e = t - mm * 136;
        nimTh[(mm * 16 + 15) * 136 + e] = 0;
        nimTl[(mm * 16 + 15) * 136 + e] = 0;
    }
    for (int t = tid; t < 128 * 29; t += 512) {
        int r = t / 29, cc = 75 + (t - r * 29);
        planes[r * 104 + cc] = 0;
    }

    const f32x4 zz = {0.f, 0.f, 0.f, 0.f};

    // ---- phase 0: nimT, 3 independent split-product chains; rolled m ----
    {
        bf16x8 ah[2], al[2];
        #pragma unroll
        for (int ks = 0; ks < 2; ++ks) {
            const float* np = node + (size_t)(w * 16 + l15) * BN + b * 64 + ks * 32 + lq * 8;
            float tmp[8];
            *(float4*)tmp       = *(const float4*)np;
            *(float4*)(tmp + 4) = *(const float4*)(np + 4);
            #pragma unroll
            for (int j = 0; j < 8; ++j) {
                ushort h_, l_; split2(tmp[j], h_, l_);
                ah[ks][j] = (short)h_; al[ks][j] = (short)l_;
            }
        }
        #pragma unroll 1
        for (int m = 0; m < Mm; ++m) {
            const float* wp = WW + ((size_t)b * Mm + m) * 960 + (l15 < 15 ? l15 : 0);
            f32x4 chh = zz, chl = zz, clh = zz;
            #pragma unroll
            for (int ks = 0; ks < 2; ++ks) {
                bf16x8 bh, bl;
                #pragma unroll
                for (int t = 0; t < 8; ++t) {
                    int n = ks * 32 + lq * 8 + t;
                    float v = (l15 < 15) ? wp[n * 15] : 0.f;
                    ushort h_, l_; split2(v, h_, l_);
                    bh[t] = (short)h_; bl[t] = (short)l_;
                }
                chh = MFMA(ah[ks], bh, chh);
                chl = MFMA(ah[ks], bl, chl);
                clh = MFMA(al[ks], bh, clh);
            }
            f32x4 c = chh + chl + clh;
            if (l15 < 15) {
                #pragma unroll
                for (int t = 0; t < 4; ++t) {
                    int e = w * 16 + lq * 4 + t;
                    split2(c[t], nimTh[(m * 16 + l15) * 136 + e],
                                 nimTl[(m * 16 + l15) * 136 + e]);
                }
            }
        }
    }
    __syncthreads();

    // ---- 4 quarters: Y-phase then swapped mask-phase; all rolled ----
    #pragma unroll 1
    for (int qd = 0; qd < 4; ++qd) {
        #pragma unroll 1
        for (int u = w; u < 10; u += 8) {
            int m = u >> 1, rt = u & 1;
            int d0 = qd * 32 + rt * 16 + l15;
            f32x4 khh = zz, khl = zz, klh = zz;
            f32x4 qhh = zz, qhl = zz, qlh = zz;
            #pragma unroll 1
            for (int ks = 0; ks < 4; ++ks) {
                int k0 = ks * 32 + lq * 8;
                size_t wo = (size_t)m * 16384 + (size_t)d0 * 128 + k0;
                bf16x8 akh = *(const bf16x8*)(WKhi + wo);
                bf16x8 akl = *(const bf16x8*)(WKlo + wo);
                bf16x8 aqh = *(const bf16x8*)(WQhi + wo);
                bf16x8 aql = *(const bf16x8*)(WQlo + wo);
                bf16x8 bh = *(const bf16x8*)(&nimTh[(m * 16 + l15) * 136 + k0]);
                bf16x8 bl = *(const bf16x8*)(&nimTl[(m * 16 + l15) * 136 + k0]);
                khh = MFMA(akh, bh, khh); khl = MFMA(akh, bl, khl); klh = MFMA(akl, bh, klh);
                qhh = MFMA(aqh, bh, qhh); qhl = MFMA(aqh, bl, qhl); qlh = MFMA(aql, bh, qlh);
            }
            f32x4 cK = khh + khl + klh;
            f32x4 cQ = qhh + qhl + qlh;
            if (l15 < 15) {
                int j = m * 15 + l15;
                #pragma unroll
                for (int t = 0; t < 4; ++t) {
                    int r = rt * 16 + lq * 4 + t;
                    split2(cK[t], Ykh[r * 104 + j], Ykl[r * 104 + j]);
                    split2(cQ[t], Yqh[r * 104 + j], Yql[r * 104 + j]);
                }
            }
        }
        __syncthreads();
        {
            // swapped: A = maskT (rows n), B = Y (rows d-local) -> C[n][dloc]
            int nr = w & 3, dc = w >> 2;
            f32x4 khh = zz, khl = zz, klh = zz;
            f32x4 qhh = zz, qhl = zz, qlh = zz;
            #pragma unroll 1
            for (int ks = 0; ks < 3; ++ks) {
                int k0 = ks * 32 + lq * 8;
                bf16x8 mh = *(const bf16x8*)(maskThi + (nr * 16 + l15) * 96 + k0);
                bf16x8 ml = *(const bf16x8*)(maskTlo + (nr * 16 + l15) * 96 + k0);
                bf16x8 ykh = *(const bf16x8*)(&Ykh[(dc * 16 + l15) * 104 + k0]);
                bf16x8 ykl = *(const bf16x8*)(&Ykl[(dc * 16 + l15) * 104 + k0]);
                bf16x8 yqh = *(const bf16x8*)(&Yqh[(dc * 16 + l15) * 104 + k0]);
                bf16x8 yql = *(const bf16x8*)(&Yql[(dc * 16 + l15) * 104 + k0]);
                khh = MFMA(mh, ykh, khh); khl = MFMA(ml, ykh, khl); klh = MFMA(mh, ykl, klh);
                qhh = MFMA(mh, yqh, qhh); qhl = MFMA(ml, yqh, qhl); qlh = MFMA(mh, yql, qlh);
            }
            f32x4 cK = khh + khl + klh;
            f32x4 cQ = qhh + qhl + qlh;
            #pragma unroll
            for (int t = 0; t < 4; ++t) {
                int n = nr * 16 + lq * 4 + t;
                int dloc = dc * 16 + l15;
                int d = qd * 32 + dloc;
                size_t oi = (((size_t)(b * 4 + qd)) * 64 + n) * 32 + dloc;
                ushort hh_, ll_;
                split2(cK[t] + btKT[n * 128 + d], hh_, ll_);
                Khi[oi] = hh_; Klo[oi] = ll_;
                split2(cQ[t] + btQT[n * 128 + d], hh_, ll_);
                Qhi[oi] = hh_; Qlo[oi] = ll_;
            }
        }
        __syncthreads();
    }

    // ---- msg scatter: xM flat (2 chains); rolled m and ks ----
    {
        int rt = w;
        #pragma unroll 1
        for (int m = 0; m < Mm; ++m) {
            f32x4 c0 = zz, c1 = zz;
            #pragma unroll 1
            for (int ks = 0; ks < 4; ++ks) {
                int k0 = ks * 32 + lq * 8;
                bf16x8 a  = *(const bf16x8*)(WMhi + (size_t)m * 16384 + (size_t)(rt * 16 + l15) * 128 + k0);
                bf16x8 bh = *(const bf16x8*)(&nimTh[(m * 16 + l15) * 136 + k0]);
                if (ks < 2) c0 = MFMA(a, bh, c0); else c1 = MFMA(a, bh, c1);
            }
            f32x4 c = c0 + c1;
            if (l15 < 15) {
                #pragma unroll
                for (int t = 0; t < 4; ++t) {
                    int dflat = rt * 16 + lq * 4 + t;
                    int g = m * 1920 + dflat * 15 + l15;
                    planes[(g / 75) * 104 + (g % 75)] = f2bf(c[t]);
                }
            }
        }
    }
    __syncthreads();
    // ---- msg mask (swapped, single bf16, 3 chains); rolled s ----
    #pragma unroll 1
    for (int s = 0; s < 4; ++s) {
        int u = w * 4 + s;
        int nr = u & 3, ddc = u >> 2;
        f32x4 cs0 = zz, cs1 = zz, cs2 = zz;
        {
            bf16x8 a0 = *(const bf16x8*)(maskThi + (nr * 16 + l15) * 96 + lq * 8);
            bf16x8 b0 = *(const bf16x8*)(&planes[(ddc * 16 + l15) * 104 + lq * 8]);
            cs0 = MFMA(a0, b0, cs0);
            bf16x8 a1 = *(const bf16x8*)(maskThi + (nr * 16 + l15) * 96 + 32 + lq * 8);
            bf16x8 b1 = *(const bf16x8*)(&planes[(ddc * 16 + l15) * 104 + 32 + lq * 8]);
            cs1 = MFMA(a1, b1, cs1);
            bf16x8 a2 = *(const bf16x8*)(maskThi + (nr * 16 + l15) * 96 + 64 + lq * 8);
            bf16x8 b2 = *(const bf16x8*)(&planes[(ddc * 16 + l15) * 104 + 64 + lq * 8]);
            cs2 = MFMA(a2, b2, cs2);
        }
        f32x4 c = cs0 + cs1 + cs2;
        #pragma unroll
        for (int t = 0; t < 4; ++t) {
            int n = nr * 16 + lq * 4 + t;
            int dd = ddc * 16 + l15;
            int h = dd >> 5, dk = dd & 31;
            msgTg[(((size_t)(b * 4 + h)) * 64 + n) * 32 + dk] = f2bf(c[t] + btMT[n * 128 + dd]);
        }
    }
}

// ---------------------------------------------------------------------------
// k2 v6 (round-6 data path; rolled q-loop): global-direct fragments, 44.3KB.
// B overlays the Qhi slice (read-then-write, same block).
// ---------------------------------------------------------------------------
__global__ __launch_bounds__(512, 4) void k2_attn(
    const ushort* __restrict__ Khi, const ushort* __restrict__ Klo,
    const ushort* Qhi, const ushort* __restrict__ Qlo,
    const ushort* __restrict__ msgTg,
    const float* __restrict__ R, const float* __restrict__ am,
    const ushort* __restrict__ WcatT, float* __restrict__ aw00,
    ushort* Bout)
{
    const int b = blockIdx.x >> 2, h = blockIdx.x & 3;
    const int tid = threadIdx.x;
    const int lane = tid & 63, w = tid >> 6;
    const int l15 = lane & 15, lq = lane >> 4;

    __shared__ float  ST[64 * 65];
    __shared__ ushort resS[128 * 72];
    __shared__ ushort awq[64 * 72];

    const f32x4 zz = {0.f, 0.f, 0.f, 0.f};
    const size_t base2 = (size_t)(b * 4 + h) * 2048;
    const float* Rb = R + (size_t)(b * 4 + h) * 4096;

    {
        int ti = w >> 1;
        bf16x8 ah = *(const bf16x8*)(Qhi + base2 + (size_t)(ti * 16 + l15) * 32 + lq * 8);
        bf16x8 al = *(const bf16x8*)(Qlo + base2 + (size_t)(ti * 16 + l15) * 32 + lq * 8);
        #pragma unroll 1
        for (int s = 0; s < 2; ++s) {
            int tj = (w & 1) * 2 + s;
            bf16x8 bh = *(const bf16x8*)(Khi + base2 + (size_t)(tj * 16 + l15) * 32 + lq * 8);
            bf16x8 bl = *(const bf16x8*)(Klo + base2 + (size_t)(tj * 16 + l15) * 32 + lq * 8);
            f32x4 chh = zz, chl = zz, clh = zz;
            chh = MFMA(ah, bh, chh); chl = MFMA(ah, bl, chl); clh = MFMA(al, bh, clh);
            f32x4 c = chh + chl + clh;
            #pragma unroll
            for (int r = 0; r < 4; ++r) {
                int i = ti * 16 + lq * 4 + r, j = tj * 16 + l15;
                ST[j * 65 + i] = Rb[i * 64 + j] + c[r] * RSQRT_DK;
            }
        }
    }
    {
        bf16x8 a = *(const bf16x8*)(WcatT + (w * 16 + l15) * 32 + lq * 8);
        #pragma unroll 1
        for (int nt = 0; nt < 4; ++nt) {
            bf16x8 bfr = *(const bf16x8*)(msgTg + base2 + (size_t)(nt * 16 + l15) * 32 + lq * 8);
            f32x4 c = MFMA(a, bfr, zz);
            #pragma unroll
            for (int r = 0; r < 4; ++r)
                resS[(w * 16 + lq * 4 + r) * 72 + nt * 16 + l15] = f2bf(c[r]);
        }
    }
    __syncthreads();

    {
        int row = tid >> 3, part = tid & 7;
        float v[8]; float mx = -INFINITY;
        #pragma unroll
        for (int jj = 0; jj < 8; ++jj) { v[jj] = ST[(part * 8 + jj) * 65 + row]; mx = fmaxf(mx, v[jj]); }
        mx = fmaxf(mx, __shfl_xor(mx, 1));
        mx = fmaxf(mx, __shfl_xor(mx, 2));
        mx = fmaxf(mx, __shfl_xor(mx, 4));
        float s = 0.f;
        #pragma unroll
        for (int jj = 0; jj < 8; ++jj) { v[jj] = expf(v[jj] - mx); s += v[jj]; }
        s += __shfl_xor(s, 1); s += __shfl_xor(s, 2); s += __shfl_xor(s, 4);
        float inv = 1.f / s;
        #pragma unroll
        for (int jj = 0; jj < 8; ++jj) {
            float p = v[jj] * inv;
            ST[(part * 8 + jj) * 65 + row] = isnan(p) ? 0.f : p;
        }
    }
    __syncthreads();

    const int kt = w >> 2, it = w & 3;
    f32x4 accB0 = zz, accB1 = zz;
    #pragma unroll 1
    for (int q = 0; q < 4; ++q) {
        for (int e = tid; e < 4096; e += 512) {
            int i = e >> 6, j0 = e & 63;
            float p = ST[j0 * 65 + i] * am[i * 256 + q * 64 + j0];
            awq[i * 72 + j0] = f2bf(p);
            if (blockIdx.x == 0) aw00[i * 256 + q * 64 + j0] = p;
        }
        __syncthreads();
        int row = 4 * (kt * 16 + l15) + q;
        bf16x8 a0 = *(const bf16x8*)(&resS[row * 72 + lq * 8]);
        bf16x8 b0 = *(const bf16x8*)(&awq[(it * 16 + l15) * 72 + lq * 8]);
        accB0 = MFMA(a0, b0, accB0);
        bf16x8 a1 = *(const bf16x8*)(&resS[row * 72 + 32 + lq * 8]);
        bf16x8 b1 = *(const bf16x8*)(&awq[(it * 16 + l15) * 72 + 32 + lq * 8]);
        accB1 = MFMA(a1, b1, accB1);
        __syncthreads();
    }
    f32x4 accB = accB0 + accB1;

    #pragma unroll
    for (int r = 0; r < 4; ++r) {
        int k = kt * 16 + lq * 4 + r, i = it * 16 + l15;
        float x = accB[r];
        float g = 0.5f * x * (1.f + erff(x * 0.70710678118654752f));
        Bout[base2 + k * 64 + i] = f2bf(g);
    }
}

// ---------------------------------------------------------------------------
// k3 (round-6 data path; rolled m and eb loops): projection + residual.
// ---------------------------------------------------------------------------
__global__ __launch_bounds__(512, 4) void k3_out(
    const ushort* Bbuf, const float* __restrict__ WW,
    const ushort* __restrict__ WBhi, const ushort* __restrict__ maskhi,
    const float* __restrict__ btB, const float* __restrict__ node,
    float* __restrict__ outp)
{
    const int b = blockIdx.x, tid = threadIdx.x;
    const int lane = tid & 63, w = tid >> 6, l15 = lane & 15, lq = lane >> 4;
    __shared__ ushort sB[128 * 72];
    __shared__ ushort wwh[64 * 17];
    __shared__ ushort t1[128 * 17];
    __shared__ ushort nm[32 * 66];

    for (int i = tid; i < 8192; i += 512) {
        int d = i >> 6, n = i & 63;
        sB[d * 72 + n] = Bbuf[(size_t)b * 8192 + i];
    }
    const f32x4 zz = {0.f, 0.f, 0.f, 0.f};
    f32x4 acc[4];
    for (int c = 0; c < 4; ++c) acc[c] = zz;
    __syncthreads();

    #pragma unroll 1
    for (int m = 0; m < Mm; ++m) {
        for (int i = tid; i < 64 * 17; i += 512) {
            int n = i / 17, N = i - n * 17;
            wwh[i] = (N < 15) ? f2bf(WW[(((size_t)b * Mm + m) * 64 + n) * 15 + N]) : (ushort)0;
        }
        __syncthreads();
        {
            f32x4 c0 = zz, c1 = zz;
            #pragma unroll 1
            for (int ks = 0; ks < 2; ++ks) {
                int k0 = ks * 32 + (lq << 3);
                bf16x8 a = *(const bf16x8*)(&sB[(w * 16 + l15) * 72 + k0]);
                bf16x8 bh;
                #pragma unroll
                for (int t = 0; t < 8; ++t) bh[t] = (short)wwh[(k0 + t) * 17 + l15];
                if (ks == 0) c0 = MFMA(a, bh, c0); else c1 = MFMA(a, bh, c1);
            }
            f32x4 c = c0 + c1;
            #pragma unroll
            for (int t = 0; t < 4; ++t)
                t1[(w * 16 + lq * 4 + t) * 17 + l15] = f2bf(c[t]);
        }
        __syncthreads();

        bf16x8 mfh;
        {
            int ct = w & 3;
            int k0 = lq << 3;
            #pragma unroll
            for (int t = 0; t < 8; ++t) {
                int kk = k0 + t;
                int row = (kk < 15) ? (m * 15 + kk) : 95;
                mfh[t] = (short)maskhi[row * 64 + ct * 16 + l15];
            }
        }
        #pragma unroll 1
        for (int eb = 0; eb < 4; ++eb) {
            {
                int rtl = w >> 2, ct = w & 3;
                int e = eb * 32 + rtl * 16 + l15;
                int k0 = lq << 3;
                bf16x8 a;
                #pragma unroll
                for (int t = 0; t < 8; ++t) {
                    int kk = k0 + t;
                    int cc = (kk < 15) ? kk : 15;
                    a[t] = (short)t1[e * 17 + cc];
                }
                f32x4 c = zz;
                c = MFMA(a, mfh, c);
                #pragma unroll
                for (int t = 0; t < 4; ++t)
                    nm[(rtl * 16 + lq * 4 + t) * 66 + ct * 16 + l15] = f2bf(c[t]);
            }
            __syncthreads();
            {
                size_t aoff = (size_t)(w * 16 + l15) * 128 + eb * 32 + (lq << 3);
                bf16x8 a = *(const bf16x8*)(WBhi + m * 16384 + aoff);
                int k0 = lq << 3;
                #pragma unroll
                for (int ct = 0; ct < 4; ++ct) {
                    bf16x8 bh;
                    #pragma unroll
                    for (int t = 0; t < 8; ++t) bh[t] = (short)nm[(k0 + t) * 66 + ct * 16 + l15];
                    acc[ct] = MFMA(a, bh, acc[ct]);
                }
            }
            __syncthreads();
        }
    }
    #pragma unroll
    for (int ct = 0; ct < 4; ++ct) {
        #pragma unroll
        for (int t = 0; t < 4; ++t) {
            int d = w * 16 + lq * 4 + t;
            int col = ct * 16 + l15;
            size_t gi = (size_t)d * BN + b * 64 + col;
            outp[gi] = acc[ct][t] + btB[d * 64 + col] + node[gi];
        }
    }
}

extern "C" void kernel_launch(void* const* d_in, const int* in_sizes, int n_in,
                              void* d_out, int out_size, void* d_ws, size_t ws_size,
                              hipStream_t stream) {
    const float* node  = (const float*)d_in[0];
    const float* WW    = (const float*)d_in[1];
    const float* maskm = (const float*)d_in[2];
    const float* R     = (const float*)d_in[3];
    const float* am    = (const float*)d_in[4];
    const float* WK = (const float*)d_in[5];  const float* bK = (const float*)d_in[6];
    const float* WQ = (const float*)d_in[7];  const float* bQ = (const float*)d_in[8];
    const float* WM = (const float*)d_in[9];  const float* bM = (const float*)d_in[10];
    const float* WB = (const float*)d_in[11]; const float* bB = (const float*)d_in[12];
    const float* Wu = (const float*)d_in[13]; const float* Wd = (const float*)d_in[14];
    const float* Wl = (const float*)d_in[15]; const float* Wr = (const float*)d_in[16];

    float* out  = (float*)d_out;
    float* aw00 = out + (size_t)Dd * BN;

    // K split planes fill the out region (dead before k3 writes out)
    ushort* Khi = (ushort*)d_out;
    ushort* Klo = Khi + 8388608;

    char* W = (char*)d_ws;
    ushort* Qhi   = (ushort*)W;                   // 16.78MB (also Bout/Bbuf)
    ushort* Qlo   = Qhi + 8388608;                // 16.78MB
    ushort* msgTg = Qlo + 8388608;                // 16.78MB
    ushort* WKhi  = msgTg + 8388608;
    ushort* WKlo  = WKhi + 81920;
    ushort* WQhi  = WKlo + 81920;
    ushort* WQlo  = WQhi + 81920;
    ushort* WMhi  = WQlo + 81920;
    ushort* WBhi  = WMhi + 81920;
    ushort* maskhi  = WBhi + 81920;
    ushort* masklo  = maskhi + 6144;
    ushort* maskThi = masklo + 6144;
    ushort* maskTlo = maskThi + 6144;
    ushort* WcatT   = maskTlo + 6144;
    float*  btKT = (float*)(WcatT + 4096);
    float*  btQT = btKT + 8192;
    float*  btMT = btQT + 8192;
    float*  btB  = btMT + 8192;

    k0_prep<<<512, 256, 0, stream>>>(maskm, WK, bK, WQ, bQ, WM, bM, WB, bB,
                                     Wu, Wd, Wl, Wr,
                                     WKhi, WKlo, WQhi, WQlo, WMhi, WBhi,
                                     maskhi, masklo, maskThi, maskTlo,
                                     btKT, btQT, btMT, btB, WcatT);
    k1_proj<<<Bb, 512, 0, stream>>>(node, WW, WKhi, WKlo, WQhi, WQlo, WMhi,
                                    maskThi, maskTlo, btKT, btQT, btMT,
                                    Khi, Klo, Qhi, Qlo, msgTg);
    k2_attn<<<Bb * Hh, 512, 0, stream>>>(Khi, Klo, Qhi, Qlo, msgTg, R, am,
                                         WcatT, aw00, Qhi /*Bout overlay*/);
    k3_out<<<Bb, 512, 0, stream>>>(Qhi /*Bbuf*/, WW, WBhi, maskhi, btB, node, out);
}